// Round 1
// baseline (22.740 us; speedup 1.0000x reference)
//
#include <hip/hip_runtime.h>

#define NPTS 2048
#define DIM  32
#define ROWS_PER_BLOCK 8
#define THREADS 256
// log(2048) = 11*ln(2)
#define LOG_M 7.6246189861593985

// Kernel 1: per-row stats of the implicit cost matrix.
//   R[i]    = sum_j exp(-||x_i - y_j||^2)
//   Crow[i] = sum_j ||x_i - y_j||^2
__global__ __launch_bounds__(THREADS)
void sink_rowstats(const float* __restrict__ x, const float* __restrict__ y,
                   float* __restrict__ R, float* __restrict__ Crow) {
    __shared__ float xs[ROWS_PER_BLOCK][DIM];
    __shared__ float redE[ROWS_PER_BLOCK][4];
    __shared__ float redC[ROWS_PER_BLOCK][4];

    const int tid = threadIdx.x;
    const int rowBase = blockIdx.x * ROWS_PER_BLOCK;

    // stage 8 x-rows (256 floats) into LDS
    xs[tid >> 5][tid & 31] = x[rowBase * DIM + tid];
    __syncthreads();

    float accE[ROWS_PER_BLOCK], accC[ROWS_PER_BLOCK];
#pragma unroll
    for (int r = 0; r < ROWS_PER_BLOCK; ++r) { accE[r] = 0.f; accC[r] = 0.f; }

    for (int j = tid; j < NPTS; j += THREADS) {
        float yv[DIM];
        const float4* yp = (const float4*)(y + j * DIM);
#pragma unroll
        for (int q = 0; q < DIM / 4; ++q) {
            float4 v = yp[q];
            yv[4*q+0] = v.x; yv[4*q+1] = v.y; yv[4*q+2] = v.z; yv[4*q+3] = v.w;
        }
#pragma unroll
        for (int r = 0; r < ROWS_PER_BLOCK; ++r) {
            float c = 0.f;
#pragma unroll
            for (int k = 0; k < DIM; ++k) {
                float d = xs[r][k] - yv[k];   // LDS read is wave-uniform -> broadcast
                c = fmaf(d, d, c);
            }
            accE[r] += __expf(-c);
            accC[r] += c;
        }
    }

    // wave (64-lane) butterfly reduce, then cross-wave via LDS
#pragma unroll
    for (int r = 0; r < ROWS_PER_BLOCK; ++r) {
#pragma unroll
        for (int off = 32; off >= 1; off >>= 1) {
            accE[r] += __shfl_xor(accE[r], off, 64);
            accC[r] += __shfl_xor(accC[r], off, 64);
        }
    }
    const int wave = tid >> 6;
    if ((tid & 63) == 0) {
#pragma unroll
        for (int r = 0; r < ROWS_PER_BLOCK; ++r) {
            redE[r][wave] = accE[r];
            redC[r][wave] = accC[r];
        }
    }
    __syncthreads();
    if (tid < ROWS_PER_BLOCK) {
        float e = redE[tid][0] + redE[tid][1] + redE[tid][2] + redE[tid][3];
        float c = redC[tid][0] + redC[tid][1] + redC[tid][2] + redC[tid][3];
        R[rowBase + tid]    = e;
        Crow[rowBase + tid] = c;
    }
}

// Kernel 2: closed-form Sinkhorn epilogue (single block).
//   w_i  = log M + log R_i
//   c50  = lse_j(-49 * w_j)
//   loss = sum_i exp(-50*w_i - c50) * Crow_i
__global__ __launch_bounds__(THREADS)
void sink_finish(const float* __restrict__ R, const float* __restrict__ Crow,
                 float* __restrict__ out) {
    __shared__ double sm[4];
    const int tid = threadIdx.x;
    const int lane = tid & 63, wave = tid >> 6;

    double w[8], cr[8];
#pragma unroll
    for (int r = 0; r < 8; ++r) {
        int i = tid + r * THREADS;
        w[r]  = LOG_M + log((double)R[i]);
        cr[r] = (double)Crow[i];
    }

    // max of -49*w
    double m = -49.0 * w[0];
#pragma unroll
    for (int r = 1; r < 8; ++r) m = fmax(m, -49.0 * w[r]);
#pragma unroll
    for (int off = 32; off >= 1; off >>= 1) m = fmax(m, __shfl_xor(m, off, 64));
    if (lane == 0) sm[wave] = m;
    __syncthreads();
    m = fmax(fmax(sm[0], sm[1]), fmax(sm[2], sm[3]));
    __syncthreads();

    // sum exp(-49*w - m)
    double s = 0.0;
#pragma unroll
    for (int r = 0; r < 8; ++r) s += exp(-49.0 * w[r] - m);
#pragma unroll
    for (int off = 32; off >= 1; off >>= 1) s += __shfl_xor(s, off, 64);
    if (lane == 0) sm[wave] = s;
    __syncthreads();
    s = sm[0] + sm[1] + sm[2] + sm[3];
    const double c50 = m + log(s);
    __syncthreads();

    // loss = sum exp(-50*w - c50) * Crow
    double loss = 0.0;
#pragma unroll
    for (int r = 0; r < 8; ++r) loss += exp(-50.0 * w[r] - c50) * cr[r];
#pragma unroll
    for (int off = 32; off >= 1; off >>= 1) loss += __shfl_xor(loss, off, 64);
    if (lane == 0) sm[wave] = loss;
    __syncthreads();
    if (tid == 0) out[0] = (float)(sm[0] + sm[1] + sm[2] + sm[3]);
}

extern "C" void kernel_launch(void* const* d_in, const int* in_sizes, int n_in,
                              void* d_out, int out_size, void* d_ws, size_t ws_size,
                              hipStream_t stream) {
    const float* x = (const float*)d_in[0];
    const float* y = (const float*)d_in[1];
    float* out = (float*)d_out;
    float* ws  = (float*)d_ws;     // needs 2*2048 floats = 16 KB
    float* R    = ws;
    float* Crow = ws + NPTS;

    sink_rowstats<<<NPTS / ROWS_PER_BLOCK, THREADS, 0, stream>>>(x, y, R, Crow);
    sink_finish<<<1, THREADS, 0, stream>>>(R, Crow, out);
}